// Round 1
// baseline (371314.966 us; speedup 1.0000x reference)
//
#include <hip/hip_runtime.h>
#include <hip/hip_bf16.h>
#include <stdint.h>

#define SEQ     8192
#define DIM     2048
#define HID     1024
#define NLAYER  5
#define NWG     256
#define CPW     8      // output columns per workgroup

// ---- workspace layout (bytes) ----
//   0     : flags[256]  (u32)  -- per-WG phase flags for device barrier
//   4096  : H[1024]     (f32)  -- hidden state
//   8192  : actA[2048]  (f32)  -- ping activation buffer
//   16384 : actB[2048]  (f32)  -- pong activation buffer
//   (memset of first 32768 bytes per call resets all of the above)

__device__ __forceinline__ uint16_t f2bf(float f) {
  union { float f; uint32_t u; } v; v.f = f;
  uint32_t r = v.u + 0x7FFFu + ((v.u >> 16) & 1u);   // round-to-nearest-even
  return (uint16_t)(r >> 16);
}
__device__ __forceinline__ float bf2f(uint16_t u) {
  union { uint32_t u; float f; } v; v.u = ((uint32_t)u) << 16; return v.f;
}

__global__ void __launch_bounds__(256)
rnn_persist(const float* __restrict__ x, const float* __restrict__ W0,
            const float* __restrict__ b0, const float* __restrict__ Wmid,
            const float* __restrict__ bmid, const float* __restrict__ Wf,
            const float* __restrict__ bfv, float* __restrict__ out,
            uint32_t* __restrict__ flags, float* __restrict__ H,
            float* __restrict__ actA, float* __restrict__ actB)
{
  // 5 layers x 8 cols x 2048 k of bf16 = 163840 B = full 160 KiB LDS
  __shared__ uint16_t wlds[NLAYER * CPW * DIM];

  const int tid  = threadIdx.x;
  const int wg   = blockIdx.x;
  const int wave = tid >> 6;
  const int lane = tid & 63;

  // ---- stage this WG's weight slice (bf16) into LDS, once per call ----
  for (int i = tid; i < NLAYER * CPW * DIM; i += 256) {
    const int l    = i >> 14;        // / (CPW*DIM)
    const int r    = i & 16383;
    const int cidx = r >> 11;        // / DIM
    const int k    = r & 2047;
    const float* Ws = (l == 0) ? W0
                    : (l <= 3 ? (Wmid + (size_t)(l - 1) * DIM * DIM) : Wf);
    wlds[i] = f2bf(Ws[(size_t)k * DIM + (wg * CPW + cidx)]);
  }
  __syncthreads();

  // each wave owns 2 adjacent output columns
  const int cidx0 = wave * 2;
  const int col0  = wg * CPW + cidx0;
  const int col1  = col0 + 1;

  float bias0[NLAYER], bias1[NLAYER];
  bias0[0] = b0[col0];              bias1[0] = b0[col1];
  bias0[1] = bmid[0 * DIM + col0];  bias1[1] = bmid[0 * DIM + col1];
  bias0[2] = bmid[1 * DIM + col0];  bias1[2] = bmid[1 * DIM + col1];
  bias0[3] = bmid[2 * DIM + col0];  bias1[3] = bmid[2 * DIM + col1];
  bias0[4] = bfv[col0];             bias1[4] = bfv[col1];

  uint32_t phase = 0;

  for (int t = 0; t < SEQ; ++t) {
    const float* __restrict__ xrow = x + (size_t)t * HID;

    #pragma unroll
    for (int l = 0; l < NLAYER; ++l) {
      const uint16_t* w0p = wlds + ((l * CPW + cidx0) * DIM);
      const uint16_t* w1p = w0p + DIM;
      float acc0 = 0.f, acc1 = 0.f;

      #pragma unroll
      for (int j = 0; j < 8; ++j) {
        const int kb = j * 256 + lane * 4;
        float4 a;
        if (l == 0) {
          // feat = [x_t | hidden], no relu
          a = (j < 4) ? *(const float4*)(xrow + kb)
                      : *(const float4*)(H + (kb - HID));
        } else {
          const float* __restrict__ src = (l & 1) ? actA : actB;
          a = *(const float4*)(src + kb);
          a.x = fmaxf(a.x, 0.f); a.y = fmaxf(a.y, 0.f);
          a.z = fmaxf(a.z, 0.f); a.w = fmaxf(a.w, 0.f);
        }
        const ushort4 wa = *(const ushort4*)(w0p + kb);   // ds_read_b64
        const ushort4 wb = *(const ushort4*)(w1p + kb);
        acc0 = fmaf(a.x, bf2f(wa.x), acc0);
        acc0 = fmaf(a.y, bf2f(wa.y), acc0);
        acc0 = fmaf(a.z, bf2f(wa.z), acc0);
        acc0 = fmaf(a.w, bf2f(wa.w), acc0);
        acc1 = fmaf(a.x, bf2f(wb.x), acc1);
        acc1 = fmaf(a.y, bf2f(wb.y), acc1);
        acc1 = fmaf(a.z, bf2f(wb.z), acc1);
        acc1 = fmaf(a.w, bf2f(wb.w), acc1);
      }

      // 64-lane tree reduction
      #pragma unroll
      for (int off = 32; off > 0; off >>= 1) {
        acc0 += __shfl_xor(acc0, off, 64);
        acc1 += __shfl_xor(acc1, off, 64);
      }

      ++phase;
      if (lane == 0) {
        const float v0 = acc0 + bias0[l];
        const float v1 = acc1 + bias1[l];
        if (l < 4) {
          float* __restrict__ dst = (l & 1) ? actB : actA;
          dst[col0] = v0; dst[col1] = v1;
        } else if (col0 < HID) {
          H[col0] = v0; H[col1] = v1;
          if (t == SEQ - 1) { out[col0] = v0; out[col1] = v1; }  // final hidden
        } else {
          float* o = out + HID + (size_t)t * HID;
          o[col0 - HID] = v0; o[col1 - HID] = v1;                // outputs[t]
        }
      }

      if (t == SEQ - 1 && l == NLAYER - 1) break;   // no barrier after last store

      // ---- device-wide barrier: release flag, poll all 256 flags ----
      __syncthreads();   // all 4 waves' stores drained to L2 before release
      if (tid == 0)
        __hip_atomic_store(&flags[wg], phase, __ATOMIC_RELEASE,
                           __HIP_MEMORY_SCOPE_AGENT);
      if (tid < 64) {    // wave 0 polls: lane i watches flags[4i..4i+3]
        const uint32_t* fp = flags + (tid << 2);
        for (;;) {
          uint32_t a0 = __hip_atomic_load(fp + 0, __ATOMIC_RELAXED, __HIP_MEMORY_SCOPE_AGENT);
          uint32_t a1 = __hip_atomic_load(fp + 1, __ATOMIC_RELAXED, __HIP_MEMORY_SCOPE_AGENT);
          uint32_t a2 = __hip_atomic_load(fp + 2, __ATOMIC_RELAXED, __HIP_MEMORY_SCOPE_AGENT);
          uint32_t a3 = __hip_atomic_load(fp + 3, __ATOMIC_RELAXED, __HIP_MEMORY_SCOPE_AGENT);
          uint32_t mn = min(min(a0, a1), min(a2, a3));
          if (__all(mn >= phase)) break;
          __builtin_amdgcn_s_sleep(1);
        }
        // acquire fence (invalidates L1 + XCD L2 so act/H reads are fresh)
        (void)__hip_atomic_load(flags, __ATOMIC_ACQUIRE, __HIP_MEMORY_SCOPE_AGENT);
      }
      __syncthreads();
    }
  }
}

extern "C" void kernel_launch(void* const* d_in, const int* in_sizes, int n_in,
                              void* d_out, int out_size, void* d_ws, size_t ws_size,
                              hipStream_t stream) {
  (void)in_sizes; (void)n_in; (void)out_size; (void)ws_size;
  const float* x    = (const float*)d_in[0];
  const float* W0   = (const float*)d_in[1];
  const float* b0   = (const float*)d_in[2];
  const float* Wmid = (const float*)d_in[3];
  const float* bmid = (const float*)d_in[4];
  const float* Wf   = (const float*)d_in[5];
  const float* bfv  = (const float*)d_in[6];
  float* out = (float*)d_out;

  uint8_t* ws = (uint8_t*)d_ws;
  uint32_t* flags = (uint32_t*)(ws + 0);
  float*    H     = (float*)(ws + 4096);
  float*    actA  = (float*)(ws + 8192);
  float*    actB  = (float*)(ws + 16384);

  // reset barrier flags + hidden state every call (graph-replay safe)
  hipMemsetAsync(d_ws, 0, 32768, stream);

  rnn_persist<<<dim3(NWG), dim3(256), 0, stream>>>(
      x, W0, b0, Wmid, bmid, Wf, bfv, out, flags, H, actA, actB);
}

// Round 2
// 261643.311 us; speedup vs baseline: 1.4192x; 1.4192x over previous
//
#include <hip/hip_runtime.h>
#include <hip/hip_bf16.h>
#include <stdint.h>

#define SEQ     8192
#define DIM     2048
#define HID     1024
#define NLAYER  5
#define NWG     256
#define CPW     8      // output columns per workgroup

// ---- workspace layout (bytes) ----
//   0     : flags[256]  (u32)  -- per-WG phase flags for device barrier
//   4096  : H[1024]     (f32)  -- hidden state
//   8192  : actA[2048]  (f32)  -- ping activation buffer
//   16384 : actB[2048]  (f32)  -- pong activation buffer
//   (memset of first 32768 bytes per call resets all of the above)

__device__ __forceinline__ uint16_t f2bf(float f) {
  union { float f; uint32_t u; } v; v.f = f;
  uint32_t r = v.u + 0x7FFFu + ((v.u >> 16) & 1u);   // round-to-nearest-even
  return (uint16_t)(r >> 16);
}
__device__ __forceinline__ float bf2f(uint16_t u) {
  union { uint32_t u; float f; } v; v.u = ((uint32_t)u) << 16; return v.f;
}

// Coherent (cross-XCD) data movement: relaxed agent-scope atomics compile to
// global_load/store with sc0 sc1 — bypass the per-XCD L2, no buffer_inv /
// buffer_wbl2 cache maintenance needed anywhere in the loop.
__device__ __forceinline__ float gload(const float* p) {
  return __hip_atomic_load(const_cast<float*>(p), __ATOMIC_RELAXED,
                           __HIP_MEMORY_SCOPE_AGENT);
}
__device__ __forceinline__ void gstore(float* p, float v) {
  __hip_atomic_store(p, v, __ATOMIC_RELAXED, __HIP_MEMORY_SCOPE_AGENT);
}

__global__ void __launch_bounds__(256, 1)
rnn_persist(const float* __restrict__ x, const float* __restrict__ W0,
            const float* __restrict__ b0, const float* __restrict__ Wmid,
            const float* __restrict__ bmid, const float* __restrict__ Wf,
            const float* __restrict__ bfv, float* __restrict__ out,
            uint32_t* __restrict__ flags, float* __restrict__ H,
            float* __restrict__ actA, float* __restrict__ actB)
{
  // 5 layers x 8 cols x 2048 k of bf16 = 163840 B = full 160 KiB LDS
  __shared__ uint16_t wlds[NLAYER * CPW * DIM];

  const int tid  = threadIdx.x;
  const int wg   = blockIdx.x;
  const int wave = tid >> 6;
  const int lane = tid & 63;

  // ---- stage this WG's weight slice (bf16) into LDS, once per call ----
  // consecutive tids read adjacent columns (32B contiguous per k-row)
  for (int i = tid; i < NLAYER * CPW * DIM; i += 256) {
    const int l = i >> 14;           // / (CPW*DIM)
    const int r = i & 16383;
    const int k = r >> 3;            // 0..2047
    const int c = r & 7;             // 0..7
    const float* Ws = (l == 0) ? W0
                    : (l <= 3 ? (Wmid + (size_t)(l - 1) * DIM * DIM) : Wf);
    wlds[(l * CPW + c) * DIM + k] = f2bf(Ws[(size_t)k * DIM + (wg * CPW + c)]);
  }
  __syncthreads();

  // each wave owns 2 adjacent output columns
  const int cidx0 = wave * 2;
  const int col0  = wg * CPW + cidx0;
  const int col1  = col0 + 1;

  float bias0[NLAYER], bias1[NLAYER];
  bias0[0] = b0[col0];              bias1[0] = b0[col1];
  bias0[1] = bmid[0 * DIM + col0];  bias1[1] = bmid[0 * DIM + col1];
  bias0[2] = bmid[1 * DIM + col0];  bias1[2] = bmid[1 * DIM + col1];
  bias0[3] = bmid[2 * DIM + col0];  bias1[3] = bmid[2 * DIM + col1];
  bias0[4] = bfv[col0];             bias1[4] = bfv[col1];

  uint32_t phase = 0;

  for (int t = 0; t < SEQ; ++t) {
    const float* __restrict__ xrow = x + (size_t)t * HID;

    #pragma unroll
    for (int l = 0; l < NLAYER; ++l) {
      const uint16_t* w0p = wlds + ((l * CPW + cidx0) * DIM);
      const uint16_t* w1p = w0p + DIM;

      // ---- gather this lane's 32 activation values (batch-issued) ----
      float av[32];
      if (l == 0) {
        #pragma unroll
        for (int j = 0; j < 4; ++j) {            // x part: plain cached loads
          const float4 a = *(const float4*)(xrow + j * 256 + lane * 4);
          av[4 * j + 0] = a.x; av[4 * j + 1] = a.y;
          av[4 * j + 2] = a.z; av[4 * j + 3] = a.w;
        }
        #pragma unroll
        for (int j = 4; j < 8; ++j) {            // hidden part: coherent loads
          const int kb = j * 256 + lane * 4 - HID;
          av[4 * j + 0] = gload(H + kb + 0);
          av[4 * j + 1] = gload(H + kb + 1);
          av[4 * j + 2] = gload(H + kb + 2);
          av[4 * j + 3] = gload(H + kb + 3);
        }
      } else {
        const float* __restrict__ src = (l & 1) ? actA : actB;
        #pragma unroll
        for (int j = 0; j < 8; ++j) {
          const int kb = j * 256 + lane * 4;
          av[4 * j + 0] = fmaxf(gload(src + kb + 0), 0.f);
          av[4 * j + 1] = fmaxf(gload(src + kb + 1), 0.f);
          av[4 * j + 2] = fmaxf(gload(src + kb + 2), 0.f);
          av[4 * j + 3] = fmaxf(gload(src + kb + 3), 0.f);
        }
      }

      // ---- dot products against LDS-resident bf16 weights ----
      float acc0 = 0.f, acc1 = 0.f;
      #pragma unroll
      for (int j = 0; j < 8; ++j) {
        const int kb = j * 256 + lane * 4;
        const ushort4 wa = *(const ushort4*)(w0p + kb);   // ds_read_b64
        const ushort4 wb = *(const ushort4*)(w1p + kb);
        acc0 = fmaf(av[4 * j + 0], bf2f(wa.x), acc0);
        acc0 = fmaf(av[4 * j + 1], bf2f(wa.y), acc0);
        acc0 = fmaf(av[4 * j + 2], bf2f(wa.z), acc0);
        acc0 = fmaf(av[4 * j + 3], bf2f(wa.w), acc0);
        acc1 = fmaf(av[4 * j + 0], bf2f(wb.x), acc1);
        acc1 = fmaf(av[4 * j + 1], bf2f(wb.y), acc1);
        acc1 = fmaf(av[4 * j + 2], bf2f(wb.z), acc1);
        acc1 = fmaf(av[4 * j + 3], bf2f(wb.w), acc1);
      }

      // ---- 64-lane tree reduction ----
      #pragma unroll
      for (int off = 32; off > 0; off >>= 1) {
        acc0 += __shfl_xor(acc0, off, 64);
        acc1 += __shfl_xor(acc1, off, 64);
      }

      ++phase;
      if (lane == 0) {
        const float v0 = acc0 + bias0[l];
        const float v1 = acc1 + bias1[l];
        if (l < 4) {
          float* __restrict__ dst = (l & 1) ? actB : actA;
          gstore(dst + col0, v0); gstore(dst + col1, v1);
        } else if (col0 < HID) {
          if (t < SEQ - 1) { gstore(H + col0, v0); gstore(H + col1, v1); }
          else             { out[col0] = v0; out[col1] = v1; }   // final hidden
        } else {
          float* o = out + HID + (size_t)t * HID;                // outputs[t]
          o[col0 - HID] = v0; o[col1 - HID] = v1;
        }
      }

      if (t == SEQ - 1 && l == NLAYER - 1) break;   // no barrier after last store

      // ---- device barrier: sc1 stores acked at L3, then flag, then poll ----
      asm volatile("s_waitcnt vmcnt(0)" ::: "memory");  // data committed at L3
      __syncthreads();                                  // all 4 waves done
      if (tid == 0)
        __hip_atomic_store(&flags[wg], phase, __ATOMIC_RELAXED,
                           __HIP_MEMORY_SCOPE_AGENT);
      if (tid < 64) {    // wave 0 polls: lane i watches flags[4i..4i+3]
        const uint32_t* fp = flags + (tid << 2);
        for (;;) {
          uint32_t a0 = __hip_atomic_load(const_cast<uint32_t*>(fp + 0), __ATOMIC_RELAXED, __HIP_MEMORY_SCOPE_AGENT);
          uint32_t a1 = __hip_atomic_load(const_cast<uint32_t*>(fp + 1), __ATOMIC_RELAXED, __HIP_MEMORY_SCOPE_AGENT);
          uint32_t a2 = __hip_atomic_load(const_cast<uint32_t*>(fp + 2), __ATOMIC_RELAXED, __HIP_MEMORY_SCOPE_AGENT);
          uint32_t a3 = __hip_atomic_load(const_cast<uint32_t*>(fp + 3), __ATOMIC_RELAXED, __HIP_MEMORY_SCOPE_AGENT);
          uint32_t mn = min(min(a0, a1), min(a2, a3));
          if (__all(mn >= phase)) break;
          __builtin_amdgcn_s_sleep(1);
        }
      }
      asm volatile("" ::: "memory");
      __syncthreads();
    }
  }
}

extern "C" void kernel_launch(void* const* d_in, const int* in_sizes, int n_in,
                              void* d_out, int out_size, void* d_ws, size_t ws_size,
                              hipStream_t stream) {
  (void)in_sizes; (void)n_in; (void)out_size; (void)ws_size;
  const float* x    = (const float*)d_in[0];
  const float* W0   = (const float*)d_in[1];
  const float* b0   = (const float*)d_in[2];
  const float* Wmid = (const float*)d_in[3];
  const float* bmid = (const float*)d_in[4];
  const float* Wf   = (const float*)d_in[5];
  const float* bfv  = (const float*)d_in[6];
  float* out = (float*)d_out;

  uint8_t* ws = (uint8_t*)d_ws;
  uint32_t* flags = (uint32_t*)(ws + 0);
  float*    H     = (float*)(ws + 4096);
  float*    actA  = (float*)(ws + 8192);
  float*    actB  = (float*)(ws + 16384);

  // reset barrier flags + hidden state every call (graph-replay safe)
  hipMemsetAsync(d_ws, 0, 32768, stream);

  rnn_persist<<<dim3(NWG), dim3(256), 0, stream>>>(
      x, W0, b0, Wmid, bmid, Wf, bfv, out, flags, H, actA, actB);
}